// Round 1
// baseline (50429.910 us; speedup 1.0000x reference)
//
#include <hip/hip_runtime.h>

#define T_LEN 1024
#define B_SZ  256
#define D_DIM 64
#define E_DIM 512
#define H_DIM 256

#define SA 552   // A-tile LDS stride (bf16 elems): K=544 + 8 pad -> 2-way bank aliasing (free)
#define SH 264   // hid-tile LDS stride: K=256 + 8 pad

using short8 = __attribute__((ext_vector_type(8))) short;
using f32x4  = __attribute__((ext_vector_type(4))) float;

static __device__ __forceinline__ unsigned short f2bf(float v) {
    unsigned u = __float_as_uint(v);
    u += 0x7FFFu + ((u >> 16) & 1u);   // RNE to bf16
    return (unsigned short)(u >> 16);
}
static __device__ __forceinline__ float fast_tanh(float x) {
    x = fminf(15.f, fmaxf(-15.f, x));
    float e = __expf(2.f * x);
    return (e - 1.f) / (e + 1.f);
}

// ---- Weight prep: pack+transpose W_in / (W_s|W_t masked-half) into bf16 [n][k] ----
// W_inT[l][side][n=256][k=544]: k<32 -> z-dim rows (side0: d=32+k, side1: d=k); k>=32 -> h row k+32
// W_stT[l][side][n=64][k=256]:  n<32 -> W_s col d=dmap(side,n); n>=32 -> W_t col d=dmap(side,n-32)
__global__ void prep_kernel(const float* __restrict__ W_in, const float* __restrict__ W_s,
                            const float* __restrict__ W_t,
                            unsigned short* __restrict__ W_inT, unsigned short* __restrict__ W_stT) {
    int idx = blockIdx.x * blockDim.x + threadIdx.x;
    int stride = gridDim.x * blockDim.x;
    const int total1 = 4 * 2 * H_DIM * 544;
    for (int i = idx; i < total1; i += stride) {
        int k = i % 544;
        int n = (i / 544) % H_DIM;
        int side = (i / (544 * H_DIM)) & 1;
        int l = i / (544 * H_DIM * 2);
        int ksrc = (k < 32) ? (side == 0 ? 32 + k : k) : (k + 32);
        W_inT[i] = f2bf(W_in[(l * 576 + ksrc) * H_DIM + n]);
    }
    const int total2 = 4 * 2 * 64 * H_DIM;
    for (int i = idx; i < total2; i += stride) {
        int k = i % H_DIM;
        int n = (i / H_DIM) % 64;
        int side = (i / (H_DIM * 64)) & 1;
        int l = i / (H_DIM * 64 * 2);
        int j = n & 31;
        int d = side ? (32 + j) : j;
        float v = (n < 32) ? W_s[(l * H_DIM + k) * D_DIM + d] : W_t[(l * H_DIM + k) * D_DIM + d];
        W_stT[i] = f2bf(v);
    }
}

// ---- Phase 1: ESN recurrence. One block per batch row; W_res/W_inp resident in VGPRs. ----
// thread (e, half): output e, K-range half*288..+288 over concat[h(512), x(64)].
__launch_bounds__(1024, 4)
__global__ void esn_kernel(const float* __restrict__ x_seq, const float* __restrict__ W_res,
                           const float* __restrict__ W_inp,
                           unsigned short* __restrict__ h_store, float* __restrict__ h_carry,
                           int t0, int tc, int first) {
    const int b    = blockIdx.x;
    const int tid  = threadIdx.x;
    const int e    = tid & 511;
    const int half = tid >> 9;
    const int kbase = half * 288;

    __shared__ float hf[E_DIM];
    __shared__ float vbuf[576];     // [ h(512) | x(64) ]
    __shared__ float part[E_DIM];

    float w[288];
    #pragma unroll
    for (int i = 0; i < 288; ++i) {
        int k = kbase + i;
        w[i] = (k < E_DIM) ? W_res[e * E_DIM + k] : W_inp[(k - E_DIM) * E_DIM + e];
    }

    if (tid < E_DIM) {
        float h0 = first ? 0.f : h_carry[b * E_DIM + tid];
        hf[tid] = h0;
        vbuf[tid] = h0;
    }
    if (tid < 32) {
        float2 xx = *reinterpret_cast<const float2*>(&x_seq[((size_t)t0 * B_SZ + b) * D_DIM + tid * 2]);
        vbuf[E_DIM + tid * 2]     = xx.x;
        vbuf[E_DIM + tid * 2 + 1] = xx.y;
    }
    __syncthreads();

    for (int tl = 0; tl < tc; ++tl) {
        const int t = t0 + tl;
        // h(t) (pre-update state) -> bf16 store for phase 2
        if (tid < E_DIM)
            h_store[((size_t)tl * B_SZ + b) * E_DIM + tid] = f2bf(hf[tid]);
        float2 xnext = {0.f, 0.f};
        if (tid < 32 && t + 1 < T_LEN)
            xnext = *reinterpret_cast<const float2*>(&x_seq[((size_t)(t + 1) * B_SZ + b) * D_DIM + tid * 2]);

        float a0 = 0.f, a1 = 0.f, a2 = 0.f, a3 = 0.f;
        #pragma unroll
        for (int i = 0; i < 288; i += 16) {
            float4 v0 = *reinterpret_cast<const float4*>(&vbuf[kbase + i]);
            float4 v1 = *reinterpret_cast<const float4*>(&vbuf[kbase + i + 4]);
            float4 v2 = *reinterpret_cast<const float4*>(&vbuf[kbase + i + 8]);
            float4 v3 = *reinterpret_cast<const float4*>(&vbuf[kbase + i + 12]);
            a0 += w[i+ 0]*v0.x + w[i+ 1]*v0.y + w[i+ 2]*v0.z + w[i+ 3]*v0.w;
            a1 += w[i+ 4]*v1.x + w[i+ 5]*v1.y + w[i+ 6]*v1.z + w[i+ 7]*v1.w;
            a2 += w[i+ 8]*v2.x + w[i+ 9]*v2.y + w[i+10]*v2.z + w[i+11]*v2.w;
            a3 += w[i+12]*v3.x + w[i+13]*v3.y + w[i+14]*v3.z + w[i+15]*v3.w;
        }
        float acc = (a0 + a1) + (a2 + a3);

        if (half == 1) part[e] = acc;
        __syncthreads();
        if (half == 0) {
            float hnew = fast_tanh(acc + part[e]);
            hf[e]   = hnew;
            vbuf[e] = hnew;
        }
        if (tid < 32 && t + 1 < T_LEN) {
            vbuf[E_DIM + tid * 2]     = xnext.x;
            vbuf[E_DIM + tid * 2 + 1] = xnext.y;
        }
        __syncthreads();
    }
    if (tid < E_DIM) h_carry[b * E_DIM + tid] = hf[tid];
}

// ---- Phase 2: flow log-likelihood, MFMA bf16. Block = 16 b x 16 t, 8 subtiles of 32 frames. ----
__launch_bounds__(256, 2)
__global__ void flow_kernel(const float* __restrict__ x_seq, const unsigned short* __restrict__ h_store,
                            const unsigned short* __restrict__ W_inT, const unsigned short* __restrict__ W_stT,
                            const float* __restrict__ b_in, const float* __restrict__ b_s,
                            const float* __restrict__ b_t, const float* __restrict__ rescale_w,
                            const int* __restrict__ seq_len, float* __restrict__ ll_part,
                            int t0, int tc) {
    const int tt   = blockIdx.x >> 4;
    const int bt   = blockIdx.x & 15;
    const int tid  = threadIdx.x;
    const int wave = tid >> 6;
    const int lane = tid & 63;

    __shared__ unsigned short abf[32 * SA];    // A = [z-masked(32) | h(512)] bf16
    __shared__ unsigned short hidbf[32 * SH];  // tanh(hid) bf16; stf aliases front 8KB
    __shared__ float zf[32][D_DIM];
    __shared__ float llacc[32];
    __shared__ float llb[16];
    float* stf = reinterpret_cast<float*>(hidbf);   // [32][64]: slope(0..31)|intercept(32..63)

    if (tid < 16) llb[tid] = 0.f;

    const int r8 = tid >> 3;    // row 0..31 (8 threads/row)
    const int c8 = tid & 7;

    for (int s = 0; s < 8; ++s) {
        const int trow = tt * 16 + 2 * s + (r8 >> 4);   // chunk-local t of row r8
        const int brow = bt * 16 + (r8 & 15);
        {   // load z0 (=x frame) fp32 and h bf16 into LDS
            const float* xp = &x_seq[((size_t)(t0 + trow) * B_SZ + brow) * D_DIM + c8 * 8];
            float4 v0 = *reinterpret_cast<const float4*>(xp);
            float4 v1 = *reinterpret_cast<const float4*>(xp + 4);
            *reinterpret_cast<float4*>(&zf[r8][c8 * 8])     = v0;
            *reinterpret_cast<float4*>(&zf[r8][c8 * 8 + 4]) = v1;
            const unsigned short* hp = &h_store[((size_t)trow * B_SZ + brow) * E_DIM + c8 * 64];
            unsigned short* ap = &abf[r8 * SA + 32 + c8 * 64];
            #pragma unroll
            for (int q = 0; q < 8; ++q)
                *reinterpret_cast<uint4*>(ap + q * 8) = *reinterpret_cast<const uint4*>(hp + q * 8);
        }
        if (tid < 32) llacc[tid] = 0.f;
        __syncthreads();

        for (int stage = 0; stage < 8; ++stage) {
            const int l = 3 - (stage >> 1);
            const int side = stage & 1;
            {   // build masked-z part of A (k=0..31)
                #pragma unroll
                for (int q = 0; q < 4; ++q) {
                    int k = c8 * 4 + q;
                    int d = side ? k : (32 + k);
                    abf[r8 * SA + k] = f2bf(zf[r8][d]);
                }
            }
            __syncthreads();

            // hid GEMM: M=32 K=544 N=256; wave w -> n in [64w,64w+64)
            const unsigned short* Wl = W_inT + (size_t)(l * 2 + side) * H_DIM * 544;
            f32x4 acc[2][4];
            #pragma unroll
            for (int mt = 0; mt < 2; ++mt)
                #pragma unroll
                for (int nt = 0; nt < 4; ++nt)
                    acc[mt][nt] = (f32x4){0.f, 0.f, 0.f, 0.f};
            const int aoff  = (lane & 15) * SA + 8 * (lane >> 4);
            const int koff  = 8 * (lane >> 4);
            for (int ks = 0; ks < 17; ++ks) {
                const int k0 = ks * 32;
                short8 a0 = *reinterpret_cast<const short8*>(&abf[aoff + k0]);
                short8 a1 = *reinterpret_cast<const short8*>(&abf[16 * SA + aoff + k0]);
                #pragma unroll
                for (int nt = 0; nt < 4; ++nt) {
                    const int n = wave * 64 + nt * 16 + (lane & 15);
                    short8 bb = *reinterpret_cast<const short8*>(&Wl[(size_t)n * 544 + k0 + koff]);
                    acc[0][nt] = __builtin_amdgcn_mfma_f32_16x16x32_bf16(a0, bb, acc[0][nt], 0, 0, 0);
                    acc[1][nt] = __builtin_amdgcn_mfma_f32_16x16x32_bf16(a1, bb, acc[1][nt], 0, 0, 0);
                }
            }
            // epilogue: tanh -> hidbf (bf16)
            #pragma unroll
            for (int mt = 0; mt < 2; ++mt)
                #pragma unroll
                for (int nt = 0; nt < 4; ++nt) {
                    const int n = wave * 64 + nt * 16 + (lane & 15);
                    const float bias = b_in[l * H_DIM + n];
                    #pragma unroll
                    for (int i = 0; i < 4; ++i) {
                        const int row = mt * 16 + (lane >> 4) * 4 + i;
                        hidbf[row * SH + n] = f2bf(fast_tanh(acc[mt][nt][i] + bias));
                    }
                }
            __syncthreads();

            // slope|intercept GEMM: M=32 K=256 N=64 (n<32: slope dims, n>=32: intercept dims)
            const unsigned short* Wst = W_stT + (size_t)(l * 2 + side) * 64 * H_DIM;
            f32x4 acc2[2];
            acc2[0] = (f32x4){0.f,0.f,0.f,0.f};
            acc2[1] = (f32x4){0.f,0.f,0.f,0.f};
            const int hoff = (lane & 15) * SH + 8 * (lane >> 4);
            const int nst  = wave * 16 + (lane & 15);
            const unsigned short* Wstn = &Wst[(size_t)nst * H_DIM + 8 * (lane >> 4)];
            #pragma unroll
            for (int ks = 0; ks < 8; ++ks) {
                const int k0 = ks * 32;
                short8 a0 = *reinterpret_cast<const short8*>(&hidbf[hoff + k0]);
                short8 a1 = *reinterpret_cast<const short8*>(&hidbf[16 * SH + hoff + k0]);
                short8 bb = *reinterpret_cast<const short8*>(&Wstn[k0]);
                acc2[0] = __builtin_amdgcn_mfma_f32_16x16x32_bf16(a0, bb, acc2[0], 0, 0, 0);
                acc2[1] = __builtin_amdgcn_mfma_f32_16x16x32_bf16(a1, bb, acc2[1], 0, 0, 0);
            }
            __syncthreads();   // all hidbf reads done before stf (alias) is overwritten
            {
                const int j = nst & 31;
                const int d = side ? (32 + j) : j;
                const bool is_s = (nst < 32);
                const float bias = is_s ? b_s[l * D_DIM + d] : b_t[l * D_DIM + d];
                const float rs = rescale_w[d];
                #pragma unroll
                for (int mt = 0; mt < 2; ++mt)
                    #pragma unroll
                    for (int i = 0; i < 4; ++i) {
                        const int row = mt * 16 + (lane >> 4) * 4 + i;
                        const float v = acc2[mt][i] + bias;
                        stf[row * 64 + nst] = is_s ? (fast_tanh(v) * rs) : v;
                    }
            }
            __syncthreads();
            {   // z-update on masked dims
                #pragma unroll
                for (int q = 0; q < 4; ++q) {
                    const int j = c8 * 4 + q;
                    const int d = side ? (32 + j) : j;
                    const float sv = stf[r8 * 64 + j];
                    const float iv = stf[r8 * 64 + 32 + j];
                    zf[r8][d] = (zf[r8][d] - iv) * __expf(-sv);
                }
            }
            // log-det: ld = -sum(slope over masked dims)   (stf read-only here, no barrier needed)
            if (tid < 32) {
                float ssum = 0.f;
                #pragma unroll
                for (int j = 0; j < 32; ++j) ssum += stf[tid * 64 + j];
                llacc[tid] -= ssum;
            }
            __syncthreads();
        } // stage

        if (tid < 32) {
            float zsum = 0.f;
            #pragma unroll
            for (int d = 0; d < D_DIM; ++d) { float z = zf[tid][d]; zsum += z * z; }
            float ll = llacc[tid] - 0.5f * zsum - 58.812066125f;   // 0.5*64*log(2*pi)
            const int tg = t0 + tt * 16 + 2 * s + (tid >> 4);
            const int bg = bt * 16 + (tid & 15);
            llacc[tid] = (tg < seq_len[bg]) ? ll : 0.f;
        }
        __syncthreads();
        if (tid < 16) llb[tid] += llacc[tid] + llacc[16 + tid];
        __syncthreads();
    } // subtiles

    if (tid < 16)
        ll_part[((t0 >> 4) + tt) * B_SZ + bt * 16 + tid] = llb[tid];
}

__global__ void reduce_kernel(const float* __restrict__ ll_part, float* __restrict__ out) {
    int b = threadIdx.x;
    float s = 0.f;
    #pragma unroll
    for (int tt = 0; tt < T_LEN / 16; ++tt) s += ll_part[tt * B_SZ + b];
    out[b] = s;
}

extern "C" void kernel_launch(void* const* d_in, const int* in_sizes, int n_in,
                              void* d_out, int out_size, void* d_ws, size_t ws_size,
                              hipStream_t stream) {
    const float* x_seq   = (const float*)d_in[0];
    const int*   seqlen  = (const int*)d_in[1];
    // d_in[2] = b_mask (fixed ones|zeros pattern, hardcoded)
    const float* W_in    = (const float*)d_in[3];
    const float* b_in    = (const float*)d_in[4];
    const float* W_s     = (const float*)d_in[5];
    const float* b_s     = (const float*)d_in[6];
    const float* W_t     = (const float*)d_in[7];
    const float* b_t     = (const float*)d_in[8];
    const float* rescale = (const float*)d_in[9];
    const float* W_res   = (const float*)d_in[10];
    const float* W_inp   = (const float*)d_in[11];

    char* ws = (char*)d_ws;
    size_t off = 0;
    unsigned short* W_inT = (unsigned short*)(ws + off); off += (size_t)4 * 2 * H_DIM * 544 * 2;
    unsigned short* W_stT = (unsigned short*)(ws + off); off += (size_t)4 * 2 * 64 * H_DIM * 2;
    float* ll_part = (float*)(ws + off); off += (size_t)(T_LEN / 16) * B_SZ * 4;
    float* h_carry = (float*)(ws + off); off += (size_t)B_SZ * E_DIM * 4;
    unsigned short* h_store = (unsigned short*)(ws + off);

    // chunk length chosen from available workspace (h_store = tc*B*E bf16)
    size_t per_t = (size_t)B_SZ * E_DIM * 2;
    size_t rem = (ws_size > off) ? (ws_size - off) : 0;
    long long tcl = (long long)(rem / per_t);
    int tc = (int)((tcl > T_LEN) ? T_LEN : tcl);
    tc &= ~15;
    if (tc < 16) tc = 16;

    prep_kernel<<<256, 256, 0, stream>>>(W_in, W_s, W_t, W_inT, W_stT);
    for (int t0 = 0; t0 < T_LEN; t0 += tc) {
        int cur = T_LEN - t0; if (cur > tc) cur = tc;
        esn_kernel<<<B_SZ, 1024, 0, stream>>>(x_seq, W_res, W_inp, h_store, h_carry, t0, cur, (t0 == 0) ? 1 : 0);
        flow_kernel<<<(cur / 16) * 16, 256, 0, stream>>>(x_seq, h_store, W_inT, W_stT, b_in, b_s, b_t,
                                                         rescale, seqlen, ll_part, t0, cur);
    }
    reduce_kernel<<<1, B_SZ, 0, stream>>>(ll_part, (float*)d_out);
}

// Round 2
// 11650.598 us; speedup vs baseline: 4.3285x; 4.3285x over previous
//
#include <hip/hip_runtime.h>

#define T_LEN 1024
#define B_SZ  256
#define D_DIM 64
#define E_DIM 512
#define H_DIM 256

#define SA 552   // flow A-tile LDS stride (bf16 elems)
#define SH 264   // flow hid-tile LDS stride
#define KP 584   // esn A-row stride (fp16 elems): 576 + 8 -> row-pair bank aliasing only (free)

using short8 = __attribute__((ext_vector_type(8))) short;
using half8  = __attribute__((ext_vector_type(8))) _Float16;
using f32x4  = __attribute__((ext_vector_type(4))) float;

static __device__ __forceinline__ unsigned short f2bf(float v) {
    unsigned u = __float_as_uint(v);
    u += 0x7FFFu + ((u >> 16) & 1u);   // RNE to bf16
    return (unsigned short)(u >> 16);
}
static __device__ __forceinline__ unsigned short f2h(float v) {
    _Float16 h = (_Float16)v;
    unsigned short u;
    __builtin_memcpy(&u, &h, 2);
    return u;
}
static __device__ __forceinline__ float h2f(unsigned short u) {
    _Float16 h;
    __builtin_memcpy(&h, &u, 2);
    return (float)h;
}
static __device__ __forceinline__ float fast_tanh(float x) {
    x = fminf(15.f, fmaxf(-15.f, x));
    float e = __expf(2.f * x);
    return (e - 1.f) / (e + 1.f);
}

// ---- Weight prep ----
// W_inT[l][side][n=256][k=544] bf16 (flow hid GEMM), W_stT[l][side][n=64][k=256] bf16,
// W_pack[n=512][k=576] fp16 (ESN): k<512 -> W_res[n][k]; k>=512 -> W_inp[k-512][n]
__global__ void prep_kernel(const float* __restrict__ W_in, const float* __restrict__ W_s,
                            const float* __restrict__ W_t, const float* __restrict__ W_res,
                            const float* __restrict__ W_inp,
                            unsigned short* __restrict__ W_inT, unsigned short* __restrict__ W_stT,
                            unsigned short* __restrict__ W_packo) {
    int idx = blockIdx.x * blockDim.x + threadIdx.x;
    int stride = gridDim.x * blockDim.x;
    const int total1 = 4 * 2 * H_DIM * 544;
    for (int i = idx; i < total1; i += stride) {
        int k = i % 544;
        int n = (i / 544) % H_DIM;
        int side = (i / (544 * H_DIM)) & 1;
        int l = i / (544 * H_DIM * 2);
        int ksrc = (k < 32) ? (side == 0 ? 32 + k : k) : (k + 32);
        W_inT[i] = f2bf(W_in[(l * 576 + ksrc) * H_DIM + n]);
    }
    const int total2 = 4 * 2 * 64 * H_DIM;
    for (int i = idx; i < total2; i += stride) {
        int k = i % H_DIM;
        int n = (i / H_DIM) % 64;
        int side = (i / (H_DIM * 64)) & 1;
        int l = i / (H_DIM * 64 * 2);
        int j = n & 31;
        int d = side ? (32 + j) : j;
        float v = (n < 32) ? W_s[(l * H_DIM + k) * D_DIM + d] : W_t[(l * H_DIM + k) * D_DIM + d];
        W_stT[i] = f2bf(v);
    }
    const int total3 = E_DIM * 576;
    for (int i = idx; i < total3; i += stride) {
        int k = i % 576;
        int n = i / 576;
        float v = (k < E_DIM) ? W_res[n * E_DIM + k] : W_inp[(k - E_DIM) * E_DIM + n];
        W_packo[i] = f2h(v);
    }
}

// ---- Phase 1: ESN recurrence as per-block MFMA GEMM chain. ----
// 16 blocks x 256 threads (4 waves). Block bb owns batch rows [16bb,16bb+16).
// Per step: C[16,512] = A[16,576]@W_pack^T, fp16 in / fp32 accum; h state lives in LDS (fp16).
__launch_bounds__(256, 1)
__global__ void esn_kernel(const float* __restrict__ x_seq, const unsigned short* __restrict__ W_pack,
                           unsigned short* __restrict__ h_store /*bf16*/,
                           unsigned short* __restrict__ h_carry /*fp16*/,
                           int t0, int tc, int first) {
    const int bb   = blockIdx.x;
    const int b0   = bb * 16;
    const int tid  = threadIdx.x;
    const int wave = tid >> 6;
    const int lane = tid & 63;

    __shared__ __align__(16) unsigned short A[16 * KP];   // [row 16][k: h(512) | x(64)]

    // init h region
    for (int i = tid; i < 16 * E_DIM; i += 256) {
        int r = i >> 9, n = i & 511;
        A[r * KP + n] = first ? (unsigned short)0 : h_carry[(b0 + r) * E_DIM + n];
    }
    // init x(t0) region
    {
        int r = tid >> 4, d4 = (tid & 15) * 4;
        float4 xv = *reinterpret_cast<const float4*>(&x_seq[((size_t)t0 * B_SZ + b0 + r) * D_DIM + d4]);
        A[r * KP + E_DIM + d4 + 0] = f2h(xv.x);
        A[r * KP + E_DIM + d4 + 1] = f2h(xv.y);
        A[r * KP + E_DIM + d4 + 2] = f2h(xv.z);
        A[r * KP + E_DIM + d4 + 3] = f2h(xv.w);
    }
    __syncthreads();

    const int arow = lane & 15;
    const int koff = 8 * (lane >> 4);
    const int nb   = wave * 128 + arow;   // B n-index base for this lane

#define BLOAD(ks, nt) (*reinterpret_cast<const half8*>(&W_pack[(size_t)(nb + (nt) * 16) * 576 + (ks) * 32 + koff]))
#define ALOAD(ks)     (*reinterpret_cast<const half8*>(&A[arow * KP + koff + (ks) * 32]))

    for (int tl = 0; tl < tc; ++tl) {
        const int t = t0 + tl;
        if (tl == 0) {   // h_store[chunk-local 0] = h(t0) (bf16)
            for (int i = tid; i < 16 * E_DIM; i += 256) {
                int r = i >> 9, n = i & 511;
                h_store[((size_t)(b0 + r)) * E_DIM + n] = f2bf(h2f(A[r * KP + n]));
            }
        }
        // prefetch x(t+1)
        float4 xn = {0.f, 0.f, 0.f, 0.f};
        const int xr = tid >> 4, xd = (tid & 15) * 4;
        if (t + 1 < T_LEN)
            xn = *reinterpret_cast<const float4*>(&x_seq[((size_t)(t + 1) * B_SZ + b0 + xr) * D_DIM + xd]);

        f32x4 acc[8];
        #pragma unroll
        for (int nt = 0; nt < 8; ++nt) acc[nt] = (f32x4){0.f, 0.f, 0.f, 0.f};

        half8 bbuf[2][8];
        #pragma unroll
        for (int nt = 0; nt < 8; ++nt) bbuf[0][nt] = BLOAD(0, nt);
        #pragma unroll
        for (int nt = 0; nt < 8; ++nt) bbuf[1][nt] = BLOAD(1, nt);
        half8 af = ALOAD(0);

        #pragma unroll
        for (int ks = 0; ks < 18; ++ks) {
            half8 an = (ks < 17) ? ALOAD(ks + 1) : af;
            #pragma unroll
            for (int nt = 0; nt < 8; ++nt)
                acc[nt] = __builtin_amdgcn_mfma_f32_16x16x32_f16(af, bbuf[ks & 1][nt], acc[nt], 0, 0, 0);
            if (ks + 2 < 18) {
                #pragma unroll
                for (int nt = 0; nt < 8; ++nt) bbuf[ks & 1][nt] = BLOAD(ks + 2, nt);
            }
            af = an;
        }
        __syncthreads();   // all A reads complete before overwrite

        // h(t+1) = tanh(acc) -> A (fp16), h_store (bf16), h_carry at chunk end
        #pragma unroll
        for (int nt = 0; nt < 8; ++nt) {
            const int n = wave * 128 + nt * 16 + arow;
            #pragma unroll
            for (int i = 0; i < 4; ++i) {
                const int row = (lane >> 4) * 4 + i;
                float hv = fast_tanh(acc[nt][i]);
                unsigned short hh = f2h(hv);
                A[row * KP + n] = hh;
                if (tl + 1 < tc)
                    h_store[((size_t)(tl + 1) * B_SZ + b0 + row) * E_DIM + n] = f2bf(hv);
                else
                    h_carry[(b0 + row) * E_DIM + n] = hh;
            }
        }
        if (t + 1 < T_LEN) {
            A[xr * KP + E_DIM + xd + 0] = f2h(xn.x);
            A[xr * KP + E_DIM + xd + 1] = f2h(xn.y);
            A[xr * KP + E_DIM + xd + 2] = f2h(xn.z);
            A[xr * KP + E_DIM + xd + 3] = f2h(xn.w);
        }
        __syncthreads();
    }
#undef BLOAD
#undef ALOAD
}

// ---- Phase 2: flow log-likelihood, MFMA bf16 (unchanged from passing version). ----
__launch_bounds__(256, 2)
__global__ void flow_kernel(const float* __restrict__ x_seq, const unsigned short* __restrict__ h_store,
                            const unsigned short* __restrict__ W_inT, const unsigned short* __restrict__ W_stT,
                            const float* __restrict__ b_in, const float* __restrict__ b_s,
                            const float* __restrict__ b_t, const float* __restrict__ rescale_w,
                            const int* __restrict__ seq_len, float* __restrict__ ll_part,
                            int t0, int tc) {
    const int tt   = blockIdx.x >> 4;
    const int bt   = blockIdx.x & 15;
    const int tid  = threadIdx.x;
    const int wave = tid >> 6;
    const int lane = tid & 63;

    __shared__ unsigned short abf[32 * SA];
    __shared__ unsigned short hidbf[32 * SH];
    __shared__ float zf[32][D_DIM];
    __shared__ float llacc[32];
    __shared__ float llb[16];
    float* stf = reinterpret_cast<float*>(hidbf);

    if (tid < 16) llb[tid] = 0.f;

    const int r8 = tid >> 3;
    const int c8 = tid & 7;

    for (int s = 0; s < 8; ++s) {
        const int trow = tt * 16 + 2 * s + (r8 >> 4);
        const int brow = bt * 16 + (r8 & 15);
        {
            const float* xp = &x_seq[((size_t)(t0 + trow) * B_SZ + brow) * D_DIM + c8 * 8];
            float4 v0 = *reinterpret_cast<const float4*>(xp);
            float4 v1 = *reinterpret_cast<const float4*>(xp + 4);
            *reinterpret_cast<float4*>(&zf[r8][c8 * 8])     = v0;
            *reinterpret_cast<float4*>(&zf[r8][c8 * 8 + 4]) = v1;
            const unsigned short* hp = &h_store[((size_t)trow * B_SZ + brow) * E_DIM + c8 * 64];
            unsigned short* ap = &abf[r8 * SA + 32 + c8 * 64];
            #pragma unroll
            for (int q = 0; q < 8; ++q)
                *reinterpret_cast<uint4*>(ap + q * 8) = *reinterpret_cast<const uint4*>(hp + q * 8);
        }
        if (tid < 32) llacc[tid] = 0.f;
        __syncthreads();

        for (int stage = 0; stage < 8; ++stage) {
            const int l = 3 - (stage >> 1);
            const int side = stage & 1;
            {
                #pragma unroll
                for (int q = 0; q < 4; ++q) {
                    int k = c8 * 4 + q;
                    int d = side ? k : (32 + k);
                    abf[r8 * SA + k] = f2bf(zf[r8][d]);
                }
            }
            __syncthreads();

            const unsigned short* Wl = W_inT + (size_t)(l * 2 + side) * H_DIM * 544;
            f32x4 acc[2][4];
            #pragma unroll
            for (int mt = 0; mt < 2; ++mt)
                #pragma unroll
                for (int nt = 0; nt < 4; ++nt)
                    acc[mt][nt] = (f32x4){0.f, 0.f, 0.f, 0.f};
            const int aoff  = (lane & 15) * SA + 8 * (lane >> 4);
            const int koff  = 8 * (lane >> 4);
            for (int ks = 0; ks < 17; ++ks) {
                const int k0 = ks * 32;
                short8 a0 = *reinterpret_cast<const short8*>(&abf[aoff + k0]);
                short8 a1 = *reinterpret_cast<const short8*>(&abf[16 * SA + aoff + k0]);
                #pragma unroll
                for (int nt = 0; nt < 4; ++nt) {
                    const int n = wave * 64 + nt * 16 + (lane & 15);
                    short8 bb = *reinterpret_cast<const short8*>(&Wl[(size_t)n * 544 + k0 + koff]);
                    acc[0][nt] = __builtin_amdgcn_mfma_f32_16x16x32_bf16(a0, bb, acc[0][nt], 0, 0, 0);
                    acc[1][nt] = __builtin_amdgcn_mfma_f32_16x16x32_bf16(a1, bb, acc[1][nt], 0, 0, 0);
                }
            }
            #pragma unroll
            for (int mt = 0; mt < 2; ++mt)
                #pragma unroll
                for (int nt = 0; nt < 4; ++nt) {
                    const int n = wave * 64 + nt * 16 + (lane & 15);
                    const float bias = b_in[l * H_DIM + n];
                    #pragma unroll
                    for (int i = 0; i < 4; ++i) {
                        const int row = mt * 16 + (lane >> 4) * 4 + i;
                        hidbf[row * SH + n] = f2bf(fast_tanh(acc[mt][nt][i] + bias));
                    }
                }
            __syncthreads();

            const unsigned short* Wst = W_stT + (size_t)(l * 2 + side) * 64 * H_DIM;
            f32x4 acc2[2];
            acc2[0] = (f32x4){0.f,0.f,0.f,0.f};
            acc2[1] = (f32x4){0.f,0.f,0.f,0.f};
            const int hoff = (lane & 15) * SH + 8 * (lane >> 4);
            const int nst  = wave * 16 + (lane & 15);
            const unsigned short* Wstn = &Wst[(size_t)nst * H_DIM + 8 * (lane >> 4)];
            #pragma unroll
            for (int ks = 0; ks < 8; ++ks) {
                const int k0 = ks * 32;
                short8 a0 = *reinterpret_cast<const short8*>(&hidbf[hoff + k0]);
                short8 a1 = *reinterpret_cast<const short8*>(&hidbf[16 * SH + hoff + k0]);
                short8 bb = *reinterpret_cast<const short8*>(&Wstn[k0]);
                acc2[0] = __builtin_amdgcn_mfma_f32_16x16x32_bf16(a0, bb, acc2[0], 0, 0, 0);
                acc2[1] = __builtin_amdgcn_mfma_f32_16x16x32_bf16(a1, bb, acc2[1], 0, 0, 0);
            }
            __syncthreads();
            {
                const int j = nst & 31;
                const int d = side ? (32 + j) : j;
                const bool is_s = (nst < 32);
                const float bias = is_s ? b_s[l * D_DIM + d] : b_t[l * D_DIM + d];
                const float rs = rescale_w[d];
                #pragma unroll
                for (int mt = 0; mt < 2; ++mt)
                    #pragma unroll
                    for (int i = 0; i < 4; ++i) {
                        const int row = mt * 16 + (lane >> 4) * 4 + i;
                        const float v = acc2[mt][i] + bias;
                        stf[row * 64 + nst] = is_s ? (fast_tanh(v) * rs) : v;
                    }
            }
            __syncthreads();
            {
                #pragma unroll
                for (int q = 0; q < 4; ++q) {
                    const int j = c8 * 4 + q;
                    const int d = side ? (32 + j) : j;
                    const float sv = stf[r8 * 64 + j];
                    const float iv = stf[r8 * 64 + 32 + j];
                    zf[r8][d] = (zf[r8][d] - iv) * __expf(-sv);
                }
            }
            if (tid < 32) {
                float ssum = 0.f;
                #pragma unroll
                for (int j = 0; j < 32; ++j) ssum += stf[tid * 64 + j];
                llacc[tid] -= ssum;
            }
            __syncthreads();
        } // stage

        if (tid < 32) {
            float zsum = 0.f;
            #pragma unroll
            for (int d = 0; d < D_DIM; ++d) { float z = zf[tid][d]; zsum += z * z; }
            float ll = llacc[tid] - 0.5f * zsum - 58.812066125f;
            const int tg = t0 + tt * 16 + 2 * s + (tid >> 4);
            const int bg = bt * 16 + (tid & 15);
            llacc[tid] = (tg < seq_len[bg]) ? ll : 0.f;
        }
        __syncthreads();
        if (tid < 16) llb[tid] += llacc[tid] + llacc[16 + tid];
        __syncthreads();
    } // subtiles

    if (tid < 16)
        ll_part[((t0 >> 4) + tt) * B_SZ + bt * 16 + tid] = llb[tid];
}

__global__ void reduce_kernel(const float* __restrict__ ll_part, float* __restrict__ out) {
    int b = threadIdx.x;
    float s = 0.f;
    #pragma unroll
    for (int tt = 0; tt < T_LEN / 16; ++tt) s += ll_part[tt * B_SZ + b];
    out[b] = s;
}

extern "C" void kernel_launch(void* const* d_in, const int* in_sizes, int n_in,
                              void* d_out, int out_size, void* d_ws, size_t ws_size,
                              hipStream_t stream) {
    const float* x_seq   = (const float*)d_in[0];
    const int*   seqlen  = (const int*)d_in[1];
    const float* W_in    = (const float*)d_in[3];
    const float* b_in    = (const float*)d_in[4];
    const float* W_s     = (const float*)d_in[5];
    const float* b_s     = (const float*)d_in[6];
    const float* W_t     = (const float*)d_in[7];
    const float* b_t     = (const float*)d_in[8];
    const float* rescale = (const float*)d_in[9];
    const float* W_res   = (const float*)d_in[10];
    const float* W_inp   = (const float*)d_in[11];

    char* ws = (char*)d_ws;
    size_t off = 0;
    unsigned short* W_inT  = (unsigned short*)(ws + off); off += (size_t)4 * 2 * H_DIM * 544 * 2;
    unsigned short* W_stT  = (unsigned short*)(ws + off); off += (size_t)4 * 2 * 64 * H_DIM * 2;
    unsigned short* W_pack = (unsigned short*)(ws + off); off += (size_t)E_DIM * 576 * 2;
    float* ll_part = (float*)(ws + off); off += (size_t)(T_LEN / 16) * B_SZ * 4;
    unsigned short* h_carry = (unsigned short*)(ws + off); off += (size_t)B_SZ * E_DIM * 2;
    unsigned short* h_store = (unsigned short*)(ws + off);

    size_t per_t = (size_t)B_SZ * E_DIM * 2;
    size_t rem = (ws_size > off) ? (ws_size - off) : 0;
    long long tcl = (long long)(rem / per_t);
    int tc = (int)((tcl > T_LEN) ? T_LEN : tcl);
    tc &= ~15;
    if (tc < 16) tc = 16;

    prep_kernel<<<256, 256, 0, stream>>>(W_in, W_s, W_t, W_res, W_inp, W_inT, W_stT, W_pack);
    for (int t0 = 0; t0 < T_LEN; t0 += tc) {
        int cur = T_LEN - t0; if (cur > tc) cur = tc;
        esn_kernel<<<16, 256, 0, stream>>>(x_seq, W_pack, h_store, h_carry, t0, cur, (t0 == 0) ? 1 : 0);
        flow_kernel<<<(cur / 16) * 16, 256, 0, stream>>>(x_seq, h_store, W_inT, W_stT, b_in, b_s, b_t,
                                                         rescale, seqlen, ll_part, t0, cur);
    }
    reduce_kernel<<<1, B_SZ, 0, stream>>>(ll_part, (float*)d_out);
}